// Round 10
// baseline (525.686 us; speedup 1.0000x reference)
//
#include <hip/hip_runtime.h>
#include <stdint.h>

#define E 128
#define W 64
#define C 1024
#define S 8
#define NBUCK 4096

typedef unsigned long long u64;
typedef unsigned int u32;

__device__ __forceinline__ float sigm(float x) { return 1.0f / (1.0f + expf(-x)); }

// Wave-level suffix-scan threshold finder over hist[4096]. 1024 threads,
// 4 buckets/thread, 3 barriers.
__device__ __forceinline__ int suffix_threshold(u32* hist, u32* wtot, int* s_B,
                                                int t, int lane, int wid) {
  const int b0 = t << 2;
  const u32 v0 = hist[b0], v1 = hist[b0 + 1], v2 = hist[b0 + 2], v3 = hist[b0 + 3];
  const u32 s3 = v3, s2 = v2 + s3, s1 = v1 + s2, s0 = v0 + s1;
  u32 incl = s0;
#pragma unroll
  for (int off = 1; off < 64; off <<= 1) {
    const u32 n = __shfl_down(incl, off, 64);
    if (lane + off < 64) incl += n;
  }
  if (lane == 0) wtot[wid] = incl;
  __syncthreads();
  u32 wsuf = 0;
  for (int i = wid + 1; i < 16; ++i) wsuf += wtot[i];
  const u32 above = wsuf + (incl - s0);
  hist[b0]     = above + s0;
  hist[b0 + 1] = above + s1;
  hist[b0 + 2] = above + s2;
  hist[b0 + 3] = above + s3;
  __syncthreads();
#pragma unroll
  for (int j = 0; j < 4; ++j) {
    const int b = b0 + j;
    const u32 here = hist[b];
    const u32 nxt = (b + 1 < NBUCK) ? hist[b + 1] : 0u;
    if (here >= 64u && nxt < 64u) *s_B = b;
  }
  __syncthreads();
  return *s_B;
}

// ---------------------------------------------------------------------------
// kStep: ONE kernel per step. grid = 64 (beam) x 1024.
//  prefetch: ent rows for this block's candidates touched at kernel start
//  R: redundant global top-64 rank over rowtop -> (parent, rid, eid)
//  G/Z/M1/M2: gather + LSTM + MLP (rconst trick) -> featl
//  S0: rel-score table (1000 rels, L2 stream)
//  S: 1 cand/thread: relsc[rid] + dot(ent_emb[eid], feat_e)
//  SM: softmax -> out;  T: per-row top-64 -> rowtop
// ---------------------------------------------------------------------------
__global__ __launch_bounds__(1024) void kStep(
    int step, int last,
    const float* __restrict__ ent_emb, const float* __restrict__ rel_emb,
    const float* __restrict__ relation,
    const float* __restrict__ W1, const float* __restrict__ b1,
    const float* __restrict__ W2, const float* __restrict__ b2,
    const float* __restrict__ lstm_k, const float* __restrict__ lstm_r,
    const float* __restrict__ lstm_b,
    const int* __restrict__ cand_rel_ids, const int* __restrict__ cand_ent_ids,
    const int* __restrict__ start_ent,
    float* __restrict__ Hst, float* __restrict__ Cst,   // each [2][W][E]
    float* __restrict__ rconstb,                         // [384]
    u64* __restrict__ rowtop,                            // [W][64]
    float* __restrict__ out)
{
  const int w = blockIdx.x, t = threadIdx.x;
  const int lane = t & 63, wid = t >> 6;
  __shared__ __align__(16) float xin[384];
  __shared__ __align__(16) float xcat2[256];   // [ent_emb[cur], hnew]
  __shared__ __align__(16) float z[512];       // lstm z; rconst at step 0
  __shared__ __align__(16) float hmid[384];
  __shared__ __align__(16) float featl[256];
  __shared__ __align__(16) float relsc[1024];  // rel-score table (1000 used)
  __shared__ float sred[16];
  __shared__ float s_m, s_inv;
  __shared__ u32 wtot[16];
  __shared__ int s_par, s_rid, s_eid, s_cnt, s_B;
  __shared__ __align__(16) unsigned char arena[32768];
  u32* hist = (u32*)arena;
  u64* coll = (u64*)arena;
  float4* zacc = (float4*)arena;

  float* Hn = Hst + (size_t)(step & 1) * W * E;
  float* Cn = Cst + (size_t)(step & 1) * W * E;
  const float* Hp = Hst + (size_t)((step + 1) & 1) * W * E;
  const float* Cp = Cst + (size_t)((step + 1) & 1) * W * E;

  // candidate ids for phase S (issued first: independent of everything)
  const size_t sbase = (size_t)step * W * C + (size_t)w * C + t;
  const int d_rid = cand_rel_ids[sbase];
  const int d_eid = cand_ent_ids[sbase];
  // L2 prefetch of this thread's ent row: 8 x 64B touches, kept alive until S.
  const float* eprow = ent_emb + (size_t)d_eid * E;
  const float pf0 = eprow[0],  pf1 = eprow[16], pf2 = eprow[32],  pf3 = eprow[48];
  const float pf4 = eprow[64], pf5 = eprow[80], pf6 = eprow[96],  pf7 = eprow[112];

  if (step == 0) {
    // ---- init + rconst = relation @ W1[256:384,:] -------------------------
    const int cur = start_ent[w];
    if (t < 128) {
      xcat2[t] = ent_emb[(size_t)cur * E + t];
      xcat2[128 + t] = 0.f;
      Hn[w * E + t] = 0.f;
      Cn[w * E + t] = 0.f;
    }
    if (t < 384) {
      const int jg = t % 96, ks = t / 96;       // 4 slices x 32 rows
      const int j0 = jg << 2, k0 = ks << 5;
      float4 acc = make_float4(0.f, 0.f, 0.f, 0.f);
#pragma unroll 8
      for (int kk = 0; kk < 32; ++kk) {
        const int k = k0 + kk;
        const float4 wt = *(const float4*)(W1 + (size_t)(256 + k) * 384 + j0);
        const float xk = relation[k];
        acc.x += xk * wt.x; acc.y += xk * wt.y;
        acc.z += xk * wt.z; acc.w += xk * wt.w;
      }
      zacc[t] = acc;
    }
    __syncthreads();
    if (t < 96) {
      float4 a = zacc[t];
#pragma unroll
      for (int sl = 1; sl < 4; ++sl) {
        const float4 bq = zacc[sl * 96 + t];
        a.x += bq.x; a.y += bq.y; a.z += bq.z; a.w += bq.w;
      }
      ((float4*)z)[t] = a;
      *(float4*)(rconstb + (t << 2)) = a;
    }
    __syncthreads();
  } else {
    // ---- R: rank rowtop, keep rank w --------------------------------------
    if (t == 0) s_cnt = 0;
    ((uint4*)hist)[t] = make_uint4(0u, 0u, 0u, 0u);
    __syncthreads();
    u64 myk[4];
#pragma unroll
    for (int j = 0; j < 4; ++j) {
      myk[j] = rowtop[t + (j << 10)];
      atomicAdd(&hist[(u32)(myk[j] >> 51) & 0xFFFu], 1u);
    }
    __syncthreads();
    const int B = suffix_threshold(hist, wtot, &s_B, t, lane, wid);
#pragma unroll
    for (int j = 0; j < 4; ++j)
      if ((int)((myk[j] >> 51) & 0xFFFull) >= B) coll[atomicAdd(&s_cnt, 1)] = myk[j];
    __syncthreads();
    const int M = s_cnt;
    for (int i = t; i < M; i += 1024) {
      const u64 ki = coll[i];
      int r = 0;
      for (int j = 0; j < M; ++j) r += (coll[j] > ki);
      if (r == w) {
        const u32 flat = ~(u32)(ki & 0xFFFFFFFFull);
        const int p = (int)(flat >> 10);
        const int sl = (int)(flat & 1023u);
        const size_t cbase = (size_t)(step - 1) * W * C + (size_t)p * C + sl;
        s_par = p;
        s_rid = cand_rel_ids[cbase];
        s_eid = cand_ent_ids[cbase];
      }
    }
    __syncthreads();
    const int par = s_par, rid = s_rid, eid = s_eid;
    // ---- G: gather --------------------------------------------------------
    if (t < 384) {
      float v;
      if (t < 128) v = rel_emb[(size_t)rid * E + t];
      else if (t < 256) v = ent_emb[(size_t)eid * E + (t - 128)];
      else v = Hp[(size_t)par * E + (t - 256)];
      xin[t] = v;
    } else if (t < 512) {
      xcat2[t - 384] = ent_emb[(size_t)eid * E + (t - 384)];
    }
    __syncthreads();
    // ---- Z: z = xin @ [K;R] + b, 8 k-slices x 48 rows, f4 cols ------------
    {
      const int ks = t >> 7, jg = t & 127;
      const int j0 = jg << 2, k0 = ks * 48;
      float4 acc = make_float4(0.f, 0.f, 0.f, 0.f);
#pragma unroll 8
      for (int kk = 0; kk < 48; ++kk) {
        const int k = k0 + kk;
        const float* Wp = (k < 256) ? (lstm_k + (size_t)k * 512 + j0)
                                    : (lstm_r + (size_t)(k - 256) * 512 + j0);
        const float4 wt = *(const float4*)Wp;
        const float xk = xin[k];
        acc.x += xk * wt.x; acc.y += xk * wt.y;
        acc.z += xk * wt.z; acc.w += xk * wt.w;
      }
      zacc[t] = acc;
    }
    __syncthreads();
    if (t < 128) {
      float4 a = zacc[t];
#pragma unroll
      for (int sl = 1; sl < 8; ++sl) {
        const float4 bq = zacc[sl * 128 + t];
        a.x += bq.x; a.y += bq.y; a.z += bq.z; a.w += bq.w;
      }
      const float4 bb = *(const float4*)(lstm_b + (t << 2));
      a.x += bb.x; a.y += bb.y; a.z += bb.z; a.w += bb.w;
      ((float4*)z)[t] = a;
    }
    __syncthreads();
    if (t < 128) {
      const float zi = z[t], zf = z[128 + t], zg = z[256 + t], zo = z[384 + t];
      const float cp = Cp[(size_t)par * E + t];
      const float cn = sigm(zf) * cp + sigm(zi) * tanhf(zg);
      const float hn = sigm(zo) * tanhf(cn);
      xcat2[128 + t] = hn;
      Hn[w * E + t] = hn;
      Cn[w * E + t] = cn;
    }
    __syncthreads();
  }

  // ---- M1: hmid = relu(xcat2 @ W1[0:256,:] + rconst + b1) ------------------
  if (t < 768) {
    const int jg = t % 96, ks = t / 96;          // 8 slices x 32 rows
    const int j0 = jg << 2, k0 = ks << 5;
    float4 acc = make_float4(0.f, 0.f, 0.f, 0.f);
#pragma unroll 8
    for (int kk = 0; kk < 32; ++kk) {
      const int k = k0 + kk;
      const float4 wt = *(const float4*)(W1 + (size_t)k * 384 + j0);
      const float xk = xcat2[k];
      acc.x += xk * wt.x; acc.y += xk * wt.y;
      acc.z += xk * wt.z; acc.w += xk * wt.w;
    }
    zacc[t] = acc;
  }
  __syncthreads();
  if (t < 96) {
    float4 a = zacc[t];
#pragma unroll
    for (int sl = 1; sl < 8; ++sl) {
      const float4 bq = zacc[sl * 96 + t];
      a.x += bq.x; a.y += bq.y; a.z += bq.z; a.w += bq.w;
    }
    const float4 rc = (step == 0) ? ((const float4*)z)[t]
                                  : *(const float4*)(rconstb + (t << 2));
    const float4 bb = *(const float4*)(b1 + (t << 2));
    float4 hv;
    hv.x = fmaxf(a.x + rc.x + bb.x, 0.f);
    hv.y = fmaxf(a.y + rc.y + bb.y, 0.f);
    hv.z = fmaxf(a.z + rc.z + bb.z, 0.f);
    hv.w = fmaxf(a.w + rc.w + bb.w, 0.f);
    ((float4*)hmid)[t] = hv;
  }
  __syncthreads();

  // ---- M2: feat = relu(hmid @ W2 + b2), 16 k-slices x 24 rows --------------
  {
    const int jg = t & 63, ks = t >> 6;
    const int j0 = jg << 2, k0 = ks * 24;
    float4 acc = make_float4(0.f, 0.f, 0.f, 0.f);
#pragma unroll 8
    for (int kk = 0; kk < 24; ++kk) {
      const int k = k0 + kk;
      const float4 wt = *(const float4*)(W2 + (size_t)k * 256 + j0);
      const float xk = hmid[k];
      acc.x += xk * wt.x; acc.y += xk * wt.y;
      acc.z += xk * wt.z; acc.w += xk * wt.w;
    }
    zacc[t] = acc;
  }
  __syncthreads();
  if (t < 64) {
    float4 a = zacc[t];
#pragma unroll
    for (int sl = 1; sl < 16; ++sl) {
      const float4 bq = zacc[sl * 64 + t];
      a.x += bq.x; a.y += bq.y; a.z += bq.z; a.w += bq.w;
    }
    const float4 bb = *(const float4*)(b2 + (t << 2));
    float4 fv;
    fv.x = fmaxf(a.x + bb.x, 0.f);
    fv.y = fmaxf(a.y + bb.y, 0.f);
    fv.z = fmaxf(a.z + bb.z, 0.f);
    fv.w = fmaxf(a.w + bb.w, 0.f);
    ((float4*)featl)[t] = fv;
  }
  __syncthreads();

  // ---- S0: rel-score table (1000 rows, contiguous L2 stream) ---------------
  if (t < 1000) {
    const float4* rp = (const float4*)(rel_emb + (size_t)t * E);
    const float4* f4 = (const float4*)featl;
    float ax = 0.f, ay = 0.f, az = 0.f, aw = 0.f;
#pragma unroll
    for (int i = 0; i < 32; ++i) {
      const float4 r = rp[i], f = f4[i];
      ax += r.x * f.x; ay += r.y * f.y; az += r.z * f.z; aw += r.w * f.w;
    }
    relsc[t] = (ax + ay) + (az + aw);
  }
  __syncthreads();

  // ---- S: score candidate t = relsc[rid] + dot(ent_row, feat_e) ------------
  float score;
  {
    const float4* ep = (const float4*)(ent_emb + (size_t)d_eid * E);
    const float4* f4 = (const float4*)featl;
    float ax = 0.f, ay = 0.f, az = 0.f, aw = 0.f;
#pragma unroll
    for (int i = 0; i < 32; ++i) {
      const float4 e = ep[i], f = f4[32 + i];
      ax += e.x * f.x; ay += e.y * f.y; az += e.z * f.z; aw += e.w * f.w;
    }
    score = relsc[d_rid] + ((ax + ay) + (az + aw));
    // consume prefetch registers (keeps the early touches alive)
    asm volatile("" :: "v"(pf0), "v"(pf1), "v"(pf2), "v"(pf3),
                       "v"(pf4), "v"(pf5), "v"(pf6), "v"(pf7));
  }

  // ---- SM: softmax ---------------------------------------------------------
  float v = score;
#pragma unroll
  for (int d = 32; d; d >>= 1) v = fmaxf(v, __shfl_xor(v, d, 64));
  if (lane == 0) sred[wid] = v;
  __syncthreads();
  if (t == 0) {
    float mm = sred[0];
#pragma unroll
    for (int i = 1; i < 16; ++i) mm = fmaxf(mm, sred[i]);
    s_m = mm;
  }
  __syncthreads();
  const float pexp = expf(score - s_m);
  v = pexp;
#pragma unroll
  for (int d = 32; d; d >>= 1) v += __shfl_xor(v, d, 64);
  if (lane == 0) sred[wid] = v;
  __syncthreads();
  if (t == 0) {
    float ss = sred[0];
#pragma unroll
    for (int i = 1; i < 16; ++i) ss += sred[i];
    s_inv = 1.f / ss;
  }
  __syncthreads();
  const float prob = pexp * s_inv;
  out[(size_t)step * W * C + (size_t)w * C + t] = prob;

  // ---- T: per-row top-64 ---------------------------------------------------
  if (!last) {
    ((uint4*)hist)[t] = make_uint4(0u, 0u, 0u, 0u);
    if (t == 0) s_cnt = 0;
    __syncthreads();
    const u32 mono = __float_as_uint(prob) | 0x80000000u;
    const u64 key = ((u64)mono << 32) | (u32)~(u32)(w * C + t);
    atomicAdd(&hist[(mono >> 19) & 0xFFFu], 1u);
    __syncthreads();
    const int B = suffix_threshold(hist, wtot, &s_B, t, lane, wid);
    if ((int)((mono >> 19) & 0xFFFu) >= B) coll[atomicAdd(&s_cnt, 1)] = key;
    __syncthreads();
    const int M = s_cnt;
    for (int i = t; i < M; i += 1024) {
      const u64 ki = coll[i];
      int r = 0;
      for (int j = 0; j < M; ++j) r += (coll[j] > ki);
      if (r < 64) rowtop[(size_t)w * 64 + r] = ki;
    }
  }
}

// ---------------------------------------------------------------------------
extern "C" void kernel_launch(void* const* d_in, const int* in_sizes, int n_in,
                              void* d_out, int out_size, void* d_ws, size_t ws_size,
                              hipStream_t stream) {
  const float* ent_emb  = (const float*)d_in[0];
  const float* rel_emb  = (const float*)d_in[1];
  const float* relation = (const float*)d_in[2];
  const float* W1 = (const float*)d_in[3];
  const float* b1 = (const float*)d_in[4];
  const float* W2 = (const float*)d_in[5];
  const float* b2 = (const float*)d_in[6];
  const float* lstm_k = (const float*)d_in[7];
  const float* lstm_r = (const float*)d_in[8];
  const float* lstm_b = (const float*)d_in[9];
  const int* cr = (const int*)d_in[10];
  const int* ce = (const int*)d_in[11];
  const int* start_ent = (const int*)d_in[12];
  float* out = (float*)d_out;

  u64* rowtop = (u64*)d_ws;                                 // W*64 u64
  float* Hst = (float*)(rowtop + (size_t)W * 64);           // 2*W*E
  float* Cst = Hst + (size_t)2 * W * E;                     // 2*W*E
  float* rconstb = Cst + (size_t)2 * W * E;                 // 384

  for (int s = 0; s < S; ++s) {
    kStep<<<W, 1024, 0, stream>>>(s, (s == S - 1) ? 1 : 0,
                                  ent_emb, rel_emb, relation, W1, b1, W2, b2,
                                  lstm_k, lstm_r, lstm_b, cr, ce, start_ent,
                                  Hst, Cst, rconstb, rowtop, out);
  }
}

// Round 11
// 282.575 us; speedup vs baseline: 1.8603x; 1.8603x over previous
//
#include <hip/hip_runtime.h>
#include <stdint.h>

#define E 128
#define W 64
#define C 1024
#define S 8
#define NBUCK 4096

typedef unsigned long long u64;
typedef unsigned int u32;

__device__ __forceinline__ float sigm(float x) { return 1.0f / (1.0f + expf(-x)); }

// Wave-level suffix-scan threshold finder over hist[4096]. 1024 threads,
// 4 buckets/thread, 3 barriers.
__device__ __forceinline__ int suffix_threshold(u32* hist, u32* wtot, int* s_B,
                                                int t, int lane, int wid) {
  const int b0 = t << 2;
  const u32 v0 = hist[b0], v1 = hist[b0 + 1], v2 = hist[b0 + 2], v3 = hist[b0 + 3];
  const u32 s3 = v3, s2 = v2 + s3, s1 = v1 + s2, s0 = v0 + s1;
  u32 incl = s0;
#pragma unroll
  for (int off = 1; off < 64; off <<= 1) {
    const u32 n = __shfl_down(incl, off, 64);
    if (lane + off < 64) incl += n;
  }
  if (lane == 0) wtot[wid] = incl;
  __syncthreads();
  u32 wsuf = 0;
  for (int i = wid + 1; i < 16; ++i) wsuf += wtot[i];
  const u32 above = wsuf + (incl - s0);
  hist[b0]     = above + s0;
  hist[b0 + 1] = above + s1;
  hist[b0 + 2] = above + s2;
  hist[b0 + 3] = above + s3;
  __syncthreads();
#pragma unroll
  for (int j = 0; j < 4; ++j) {
    const int b = b0 + j;
    const u32 here = hist[b];
    const u32 nxt = (b + 1 < NBUCK) ? hist[b + 1] : 0u;
    if (here >= 64u && nxt < 64u) *s_B = b;
  }
  __syncthreads();
  return *s_B;
}

// ---------------------------------------------------------------------------
// kA: per-beam serial chain. grid = 64 x 1024.
//  step 0: init H/C, xcat from start_ent, rconst = relation @ W1[256:384,:]
//  step>0: rank rowtop (keep rank w) -> gather -> z-GEMV -> gates
//  always: M1 (rconst trick) + M2 -> featb[w][256]
// ---------------------------------------------------------------------------
__global__ __launch_bounds__(1024) void kA(
    int step,
    const float* __restrict__ ent_emb, const float* __restrict__ rel_emb,
    const float* __restrict__ relation,
    const float* __restrict__ W1, const float* __restrict__ b1,
    const float* __restrict__ W2, const float* __restrict__ b2,
    const float* __restrict__ lstm_k, const float* __restrict__ lstm_r,
    const float* __restrict__ lstm_b,
    const int* __restrict__ cand_rel_ids, const int* __restrict__ cand_ent_ids,
    const int* __restrict__ start_ent,
    float* __restrict__ Hst, float* __restrict__ Cst,   // each [2][W][E]
    float* __restrict__ rconstb,                         // [384]
    const u64* __restrict__ rowtop,                      // [W][64]
    float* __restrict__ featb)                           // [W][256]
{
  const int w = blockIdx.x, t = threadIdx.x;
  const int lane = t & 63, wid = t >> 6;
  __shared__ __align__(16) float xin[384];
  __shared__ __align__(16) float xcat2[256];   // [ent_emb[cur], hnew]
  __shared__ __align__(16) float z[512];       // lstm z; rconst at step 0
  __shared__ __align__(16) float hmid[384];
  __shared__ float sredpad[16];
  __shared__ u32 wtot[16];
  __shared__ int s_par, s_rid, s_eid, s_cnt, s_B;
  __shared__ __align__(16) unsigned char arena[32768];
  u32* hist = (u32*)arena;
  u64* coll = (u64*)arena;
  float4* zacc = (float4*)arena;
  (void)sredpad;

  float* Hn = Hst + (size_t)(step & 1) * W * E;
  float* Cn = Cst + (size_t)(step & 1) * W * E;
  const float* Hp = Hst + (size_t)((step + 1) & 1) * W * E;
  const float* Cp = Cst + (size_t)((step + 1) & 1) * W * E;

  if (step == 0) {
    // ---- init + rconst = relation @ W1[256:384,:] -------------------------
    const int cur = start_ent[w];
    if (t < 128) {
      xcat2[t] = ent_emb[(size_t)cur * E + t];
      xcat2[128 + t] = 0.f;
      Hn[w * E + t] = 0.f;
      Cn[w * E + t] = 0.f;
    }
    if (t < 384) {
      const int jg = t % 96, ks = t / 96;       // 4 slices x 32 rows
      const int j0 = jg << 2, k0 = ks << 5;
      float4 acc = make_float4(0.f, 0.f, 0.f, 0.f);
#pragma unroll 8
      for (int kk = 0; kk < 32; ++kk) {
        const int k = k0 + kk;
        const float4 wt = *(const float4*)(W1 + (size_t)(256 + k) * 384 + j0);
        const float xk = relation[k];
        acc.x += xk * wt.x; acc.y += xk * wt.y;
        acc.z += xk * wt.z; acc.w += xk * wt.w;
      }
      zacc[t] = acc;
    }
    __syncthreads();
    if (t < 96) {
      float4 a = zacc[t];
#pragma unroll
      for (int sl = 1; sl < 4; ++sl) {
        const float4 bq = zacc[sl * 96 + t];
        a.x += bq.x; a.y += bq.y; a.z += bq.z; a.w += bq.w;
      }
      ((float4*)z)[t] = a;
      *(float4*)(rconstb + (t << 2)) = a;
    }
    __syncthreads();
  } else {
    // ---- R: rank rowtop, keep rank w --------------------------------------
    if (t == 0) s_cnt = 0;
    ((uint4*)hist)[t] = make_uint4(0u, 0u, 0u, 0u);
    __syncthreads();
    u64 myk[4];
#pragma unroll
    for (int j = 0; j < 4; ++j) {
      myk[j] = rowtop[t + (j << 10)];
      atomicAdd(&hist[(u32)(myk[j] >> 51) & 0xFFFu], 1u);
    }
    __syncthreads();
    const int B = suffix_threshold(hist, wtot, &s_B, t, lane, wid);
#pragma unroll
    for (int j = 0; j < 4; ++j)
      if ((int)((myk[j] >> 51) & 0xFFFull) >= B) coll[atomicAdd(&s_cnt, 1)] = myk[j];
    __syncthreads();
    const int M = s_cnt;
    for (int i = t; i < M; i += 1024) {
      const u64 ki = coll[i];
      int r = 0;
      for (int j = 0; j < M; ++j) r += (coll[j] > ki);
      if (r == w) {
        const u32 flat = ~(u32)(ki & 0xFFFFFFFFull);
        const int p = (int)(flat >> 10);
        const int sl = (int)(flat & 1023u);
        const size_t cbase = (size_t)(step - 1) * W * C + (size_t)p * C + sl;
        s_par = p;
        s_rid = cand_rel_ids[cbase];
        s_eid = cand_ent_ids[cbase];
      }
    }
    __syncthreads();
    const int par = s_par, rid = s_rid, eid = s_eid;
    // ---- G: gather --------------------------------------------------------
    if (t < 384) {
      float v;
      if (t < 128) v = rel_emb[(size_t)rid * E + t];
      else if (t < 256) v = ent_emb[(size_t)eid * E + (t - 128)];
      else v = Hp[(size_t)par * E + (t - 256)];
      xin[t] = v;
    } else if (t < 512) {
      xcat2[t - 384] = ent_emb[(size_t)eid * E + (t - 384)];
    }
    __syncthreads();
    // ---- Z: z = xin @ [K;R] + b, 8 k-slices x 48 rows, f4 cols ------------
    {
      const int ks = t >> 7, jg = t & 127;
      const int j0 = jg << 2, k0 = ks * 48;
      float4 acc = make_float4(0.f, 0.f, 0.f, 0.f);
#pragma unroll 8
      for (int kk = 0; kk < 48; ++kk) {
        const int k = k0 + kk;
        const float* Wp = (k < 256) ? (lstm_k + (size_t)k * 512 + j0)
                                    : (lstm_r + (size_t)(k - 256) * 512 + j0);
        const float4 wt = *(const float4*)Wp;
        const float xk = xin[k];
        acc.x += xk * wt.x; acc.y += xk * wt.y;
        acc.z += xk * wt.z; acc.w += xk * wt.w;
      }
      zacc[t] = acc;
    }
    __syncthreads();
    if (t < 128) {
      float4 a = zacc[t];
#pragma unroll
      for (int sl = 1; sl < 8; ++sl) {
        const float4 bq = zacc[sl * 128 + t];
        a.x += bq.x; a.y += bq.y; a.z += bq.z; a.w += bq.w;
      }
      const float4 bb = *(const float4*)(lstm_b + (t << 2));
      a.x += bb.x; a.y += bb.y; a.z += bb.z; a.w += bb.w;
      ((float4*)z)[t] = a;
    }
    __syncthreads();
    if (t < 128) {
      const float zi = z[t], zf = z[128 + t], zg = z[256 + t], zo = z[384 + t];
      const float cp = Cp[(size_t)par * E + t];
      const float cn = sigm(zf) * cp + sigm(zi) * tanhf(zg);
      const float hn = sigm(zo) * tanhf(cn);
      xcat2[128 + t] = hn;
      Hn[w * E + t] = hn;
      Cn[w * E + t] = cn;
    }
    __syncthreads();
  }

  // ---- M1: hmid = relu(xcat2 @ W1[0:256,:] + rconst + b1) ------------------
  if (t < 768) {
    const int jg = t % 96, ks = t / 96;          // 8 slices x 32 rows
    const int j0 = jg << 2, k0 = ks << 5;
    float4 acc = make_float4(0.f, 0.f, 0.f, 0.f);
#pragma unroll 8
    for (int kk = 0; kk < 32; ++kk) {
      const int k = k0 + kk;
      const float4 wt = *(const float4*)(W1 + (size_t)k * 384 + j0);
      const float xk = xcat2[k];
      acc.x += xk * wt.x; acc.y += xk * wt.y;
      acc.z += xk * wt.z; acc.w += xk * wt.w;
    }
    zacc[t] = acc;
  }
  __syncthreads();
  if (t < 96) {
    float4 a = zacc[t];
#pragma unroll
    for (int sl = 1; sl < 8; ++sl) {
      const float4 bq = zacc[sl * 96 + t];
      a.x += bq.x; a.y += bq.y; a.z += bq.z; a.w += bq.w;
    }
    const float4 rc = (step == 0) ? ((const float4*)z)[t]
                                  : *(const float4*)(rconstb + (t << 2));
    const float4 bb = *(const float4*)(b1 + (t << 2));
    float4 hv;
    hv.x = fmaxf(a.x + rc.x + bb.x, 0.f);
    hv.y = fmaxf(a.y + rc.y + bb.y, 0.f);
    hv.z = fmaxf(a.z + rc.z + bb.z, 0.f);
    hv.w = fmaxf(a.w + rc.w + bb.w, 0.f);
    ((float4*)hmid)[t] = hv;
  }
  __syncthreads();

  // ---- M2: feat = relu(hmid @ W2 + b2), 16 k-slices x 24 rows --------------
  {
    const int jg = t & 63, ks = t >> 6;
    const int j0 = jg << 2, k0 = ks * 24;
    float4 acc = make_float4(0.f, 0.f, 0.f, 0.f);
#pragma unroll 8
    for (int kk = 0; kk < 24; ++kk) {
      const int k = k0 + kk;
      const float4 wt = *(const float4*)(W2 + (size_t)k * 256 + j0);
      const float xk = hmid[k];
      acc.x += xk * wt.x; acc.y += xk * wt.y;
      acc.z += xk * wt.z; acc.w += xk * wt.w;
    }
    zacc[t] = acc;
  }
  __syncthreads();
  if (t < 64) {
    float4 a = zacc[t];
#pragma unroll
    for (int sl = 1; sl < 16; ++sl) {
      const float4 bq = zacc[sl * 64 + t];
      a.x += bq.x; a.y += bq.y; a.z += bq.z; a.w += bq.w;
    }
    const float4 bb = *(const float4*)(b2 + (t << 2));
    float4 fv;
    fv.x = fmaxf(a.x + bb.x, 0.f);
    fv.y = fmaxf(a.y + bb.y, 0.f);
    fv.z = fmaxf(a.z + bb.z, 0.f);
    fv.w = fmaxf(a.w + bb.w, 0.f);
    ((float4*)(featb + (size_t)w * 256))[t] = fv;
  }
}

// ---------------------------------------------------------------------------
// kB: gather-bound scoring, 4 threads/candidate. grid = 512 x 512. (R5-proven)
// ---------------------------------------------------------------------------
__global__ __launch_bounds__(512) void kB(
    int step,
    const float* __restrict__ ent_emb, const float* __restrict__ rel_emb,
    const int* __restrict__ cand_rel_ids, const int* __restrict__ cand_ent_ids,
    const float* __restrict__ featb, float* __restrict__ scoresb)
{
  const int b = blockIdx.x, tid = threadIdx.x;
  const int w = b >> 3, c0 = (b & 7) << 7;
  __shared__ __align__(16) float featl[256];
  __shared__ int srid[128], seid[128];

  const size_t idbase = (size_t)step * W * C + (size_t)w * C + c0;
  if (tid < 256) featl[tid] = featb[(size_t)w * 256 + tid];
  else if (tid < 384) srid[tid - 256] = cand_rel_ids[idbase + (tid - 256)];
  else seid[tid - 384] = cand_ent_ids[idbase + (tid - 384)];
  __syncthreads();

  const int cl = tid >> 2, j = tid & 3;
  const float4* rp = (const float4*)(rel_emb + (size_t)srid[cl] * E);
  const float4* ep = (const float4*)(ent_emb + (size_t)seid[cl] * E);
  const float4* f4 = (const float4*)featl;
  float ax = 0.f, ay = 0.f, az = 0.f, aw = 0.f;
#pragma unroll
  for (int i = 0; i < 8; ++i) {
    const float4 r = rp[j + 4 * i], f = f4[j + 4 * i];
    ax += r.x * f.x; ay += r.y * f.y; az += r.z * f.z; aw += r.w * f.w;
  }
#pragma unroll
  for (int i = 0; i < 8; ++i) {
    const float4 e = ep[j + 4 * i], f = f4[32 + j + 4 * i];
    ax += e.x * f.x; ay += e.y * f.y; az += e.z * f.z; aw += e.w * f.w;
  }
  float acc = (ax + ay) + (az + aw);
  acc += __shfl_xor(acc, 1, 64);
  acc += __shfl_xor(acc, 2, 64);
  if (j == 0) scoresb[(size_t)w * C + c0 + cl] = acc;
}

// ---------------------------------------------------------------------------
// kC: softmax -> out, per-row top-64 -> rowtop. grid = 64 x 1024.
// ---------------------------------------------------------------------------
__global__ __launch_bounds__(1024) void kC(
    int step, int last, const float* __restrict__ scoresb,
    float* __restrict__ out, u64* __restrict__ rowtop)
{
  const int w = blockIdx.x, t = threadIdx.x;
  const int lane = t & 63, wid = t >> 6;
  __shared__ float sred[16];
  __shared__ float s_m, s_inv;
  __shared__ u32 wtot[16];
  __shared__ int s_cnt, s_B;
  __shared__ __align__(16) unsigned char arena[32768];
  u32* hist = (u32*)arena;
  u64* coll = (u64*)arena;

  const float score = scoresb[(size_t)w * C + t];

  float v = score;
#pragma unroll
  for (int d = 32; d; d >>= 1) v = fmaxf(v, __shfl_xor(v, d, 64));
  if (lane == 0) sred[wid] = v;
  __syncthreads();
  if (t == 0) {
    float mm = sred[0];
#pragma unroll
    for (int i = 1; i < 16; ++i) mm = fmaxf(mm, sred[i]);
    s_m = mm;
  }
  __syncthreads();
  const float pexp = expf(score - s_m);
  v = pexp;
#pragma unroll
  for (int d = 32; d; d >>= 1) v += __shfl_xor(v, d, 64);
  if (lane == 0) sred[wid] = v;
  __syncthreads();
  if (t == 0) {
    float ss = sred[0];
#pragma unroll
    for (int i = 1; i < 16; ++i) ss += sred[i];
    s_inv = 1.f / ss;
  }
  __syncthreads();
  const float prob = pexp * s_inv;
  out[(size_t)step * W * C + (size_t)w * C + t] = prob;

  if (!last) {
    ((uint4*)hist)[t] = make_uint4(0u, 0u, 0u, 0u);
    if (t == 0) s_cnt = 0;
    __syncthreads();
    const u32 mono = __float_as_uint(prob) | 0x80000000u;
    const u64 key = ((u64)mono << 32) | (u32)~(u32)(w * C + t);
    atomicAdd(&hist[(mono >> 19) & 0xFFFu], 1u);
    __syncthreads();
    const int B = suffix_threshold(hist, wtot, &s_B, t, lane, wid);
    if ((int)((mono >> 19) & 0xFFFu) >= B) coll[atomicAdd(&s_cnt, 1)] = key;
    __syncthreads();
    const int M = s_cnt;
    for (int i = t; i < M; i += 1024) {
      const u64 ki = coll[i];
      int r = 0;
      for (int j = 0; j < M; ++j) r += (coll[j] > ki);
      if (r < 64) rowtop[(size_t)w * 64 + r] = ki;
    }
  }
}

// ---------------------------------------------------------------------------
extern "C" void kernel_launch(void* const* d_in, const int* in_sizes, int n_in,
                              void* d_out, int out_size, void* d_ws, size_t ws_size,
                              hipStream_t stream) {
  const float* ent_emb  = (const float*)d_in[0];
  const float* rel_emb  = (const float*)d_in[1];
  const float* relation = (const float*)d_in[2];
  const float* W1 = (const float*)d_in[3];
  const float* b1 = (const float*)d_in[4];
  const float* W2 = (const float*)d_in[5];
  const float* b2 = (const float*)d_in[6];
  const float* lstm_k = (const float*)d_in[7];
  const float* lstm_r = (const float*)d_in[8];
  const float* lstm_b = (const float*)d_in[9];
  const int* cr = (const int*)d_in[10];
  const int* ce = (const int*)d_in[11];
  const int* start_ent = (const int*)d_in[12];
  float* out = (float*)d_out;

  u64* rowtop = (u64*)d_ws;                                 // W*64 u64
  float* Hst = (float*)(rowtop + (size_t)W * 64);           // 2*W*E
  float* Cst = Hst + (size_t)2 * W * E;                     // 2*W*E
  float* rconstb = Cst + (size_t)2 * W * E;                 // 384
  float* featb = rconstb + 384;                             // W*256
  float* scoresb = featb + (size_t)W * 256;                 // W*C

  for (int s = 0; s < S; ++s) {
    kA<<<W, 1024, 0, stream>>>(s, ent_emb, rel_emb, relation, W1, b1, W2, b2,
                               lstm_k, lstm_r, lstm_b, cr, ce, start_ent,
                               Hst, Cst, rconstb, rowtop, featb);
    kB<<<512, 512, 0, stream>>>(s, ent_emb, rel_emb, cr, ce, featb, scoresb);
    kC<<<W, 1024, 0, stream>>>(s, (s == S - 1) ? 1 : 0, scoresb, out, rowtop);
  }
}